// Round 4
// baseline (454.837 us; speedup 1.0000x reference)
//
#include <hip/hip_runtime.h>

#define MULV 32
#define BASE 9
#define ROW 288          // MULV*BASE
#define NPATH 11
#define W3J_SZ 729       // 9*9*9
#define PACK_STRIDE 384  // 363 packed coeffs per u, padded
#define PACK_TOTAL (MULV * PACK_STRIDE)   // 12288 floats
#define TILE 64          // edges per block in contract
#define LSTR 289         // LDS row stride (floats): 288 + 1 pad -> conflict-free column reads

// Path table: (i1,i2,io) blocks for IRREPS [(0,e),(1,o),(2,e)], dims {1,3,5}, offs {0,1,4}
// Blocks are disjoint cells of the 9x9x9 cube; values read from input w3j at runtime.
__device__ constexpr int p_o1[NPATH] = {0,1,4, 0,1,1,4, 0,1,4,4};
__device__ constexpr int p_d1[NPATH] = {1,3,5, 1,3,3,5, 1,3,5,5};
__device__ constexpr int p_o2[NPATH] = {0,1,4, 1,0,4,1, 4,1,0,4};
__device__ constexpr int p_d2[NPATH] = {1,3,5, 3,1,5,3, 5,3,1,5};
__device__ constexpr int p_o3[NPATH] = {0,0,0, 1,1,1,1, 4,4,4,4};
__device__ constexpr int p_d3[NPATH] = {1,1,1, 3,3,3,3, 5,5,5,5};
__device__ constexpr int voloff[NPATH + 1] = {0,1,10,35,44,53,98,143,168,213,238,363};

// ---- ws layout ----
// packed : ws[0 .. PACK_TOTAL)
// x2s    : ws + PACK_TOTAL, N*ROW floats
// count  : (int*) after x2s, N ints
// offset : count + N
// cursor : count + 2N
// bucket : count + 3N, E ints

__global__ void zero_count_kernel(float* __restrict__ ws, const int* __restrict__ dN) {
    int N = dN[0];
    int* count = (int*)(ws + PACK_TOTAL + (long)N * ROW);
    for (int i = blockIdx.x * blockDim.x + threadIdx.x; i < N; i += gridDim.x * blockDim.x)
        count[i] = 0;
}

__global__ void hist_kernel(const int* __restrict__ idxs, float* __restrict__ ws,
                            const int* __restrict__ dN, int E) {
    int N = dN[0];
    int* count = (int*)(ws + PACK_TOTAL + (long)N * ROW);
    int t = blockIdx.x * blockDim.x + threadIdx.x;
    if (t < E) atomicAdd(&count[idxs[t]], 1);
}

// single-block exclusive scan: offset[i] = sum count[0..i); also copy to cursor
__global__ void scan_kernel(float* __restrict__ ws, const int* __restrict__ dN) {
    int N = dN[0];
    int* count  = (int*)(ws + PACK_TOTAL + (long)N * ROW);
    int* offset = count + N;
    int* cursor = count + 2 * N;
    __shared__ int buf[1024];
    __shared__ int carry_s;
    if (threadIdx.x == 0) carry_s = 0;
    __syncthreads();
    for (int base = 0; base < N; base += 1024) {
        int i = base + (int)threadIdx.x;
        int v = (i < N) ? count[i] : 0;
        buf[threadIdx.x] = v;
        __syncthreads();
        #pragma unroll
        for (int off = 1; off < 1024; off <<= 1) {
            int t = (threadIdx.x >= off) ? buf[threadIdx.x - off] : 0;
            __syncthreads();
            buf[threadIdx.x] += t;
            __syncthreads();
        }
        int excl = carry_s + buf[threadIdx.x] - v;
        if (i < N) { offset[i] = excl; cursor[i] = excl; }
        __syncthreads();
        if (threadIdx.x == 0) carry_s += buf[1023];
        __syncthreads();
    }
}

__global__ void fill_kernel(const int* __restrict__ idxs, float* __restrict__ ws,
                            const int* __restrict__ dN, int E) {
    int N = dN[0];
    int* count  = (int*)(ws + PACK_TOTAL + (long)N * ROW);
    int* cursor = count + 2 * N;
    int* bucket = count + 3 * N;
    int t = blockIdx.x * blockDim.x + threadIdx.x;
    if (t < E) {
        int n = idxs[t];
        int pos = atomicAdd(&cursor[n], 1);
        bucket[pos] = t;
    }
}

// one wave per node: x2s[n,:] = sum over edges in bucket of x2[e,:]
__global__ __launch_bounds__(256) void gather_sum_kernel(const float* __restrict__ x2,
                                                         float* __restrict__ ws,
                                                         const int* __restrict__ dN) {
    int N = dN[0];
    float* x2s  = ws + PACK_TOTAL;
    int* count  = (int*)(x2s + (long)N * ROW);
    int* offset = count + N;
    int* bucket = count + 3 * N;
    const int lane = threadIdx.x & 63;
    const int wv   = threadIdx.x >> 6;
    for (int n0 = blockIdx.x * 4 + wv; n0 < N; n0 += gridDim.x * 4) {
        int n   = __builtin_amdgcn_readfirstlane(n0);
        int off = offset[n];
        int deg = count[n];
        float4 a0 = make_float4(0.f, 0.f, 0.f, 0.f);
        float4 a1 = make_float4(0.f, 0.f, 0.f, 0.f);
        for (int d = 0; d < deg; ++d) {
            int e = bucket[off + d];
            const float4* row = (const float4*)(x2 + (long)e * ROW);
            float4 v = row[lane];
            a0.x += v.x; a0.y += v.y; a0.z += v.z; a0.w += v.w;
            if (lane < 8) {
                float4 w = row[64 + lane];
                a1.x += w.x; a1.y += w.y; a1.z += w.z; a1.w += w.w;
            }
        }
        float4* orow = (float4*)(x2s + (long)n * ROW);
        orow[lane] = a0;
        if (lane < 8) orow[64 + lane] = a1;
    }
}

// packed[u][pos] = weights[u,p] * w3j[p, cell(pos)]
__global__ void ww_build_kernel(const float* __restrict__ weights,
                                const float* __restrict__ w3j,
                                float* __restrict__ packed) {
    int u = blockIdx.x;
    for (int t = threadIdx.x; t < 363; t += blockDim.x) {
        int p = 0;
        while (t >= voloff[p + 1]) ++p;
        int local = t - voloff[p];
        int d2 = p_d2[p], d3 = p_d3[p];
        int k = local % d3;
        int j = (local / d3) % d2;
        int i = local / (d3 * d2);
        int idx = (p_o1[p] + i) * 81 + (p_o2[p] + j) * 9 + (p_o3[p] + k);
        packed[u * PACK_STRIDE + t] = weights[u * NPATH + p] * w3j[p * W3J_SZ + idx];
    }
}

// Block = 256 threads = 4 waves, tile = 64 edges.
// Coalesced float4 copy of x1 tile -> LDS; lane<->edge, wave wv owns u in [wv*8, wv*8+8)
// so u stays wave-uniform -> coefficients are s_load/SGPR operands of v_fmac.
__global__ __launch_bounds__(256) void contract_kernel(
    const float* __restrict__ x1, const int* __restrict__ idxs,
    const float* __restrict__ ws, float* __restrict__ out, int E)
{
    __shared__ float lx1[TILE * LSTR];
    const int tid = threadIdx.x;
    const long ebase = (long)blockIdx.x * TILE;
    const float* __restrict__ packed = ws;
    const float* __restrict__ x2s    = ws + PACK_TOTAL;

    // coalesced tile load: 64 rows x 72 float4 = 4608 float4s, 18 per thread
    for (int q = tid; q < TILE * (ROW / 4); q += 256) {
        int r = q / (ROW / 4);
        int c = q - r * (ROW / 4);
        long e = ebase + r;
        if (e < (long)E) {
            float4 v = ((const float4*)(x1 + e * ROW))[c];
            float* d = &lx1[r * LSTR + c * 4];
            d[0] = v.x; d[1] = v.y; d[2] = v.z; d[3] = v.w;
        }
    }
    __syncthreads();

    const int lane = tid & 63;
    const int wv   = tid >> 6;
    const long e   = ebase + lane;
    const bool vld = (e < (long)E);
    const long esafe = vld ? e : 0;
    const int n = idxs[esafe];
    const float* __restrict__ r2 = x2s + (long)n * ROW;
    float* __restrict__ ro = out + esafe * ROW;
    const float* __restrict__ lrow = &lx1[lane * LSTR];

    #pragma unroll 1
    for (int uu = 0; uu < MULV / 4; ++uu) {
        const int u = (wv << 3) + uu;               // wave-uniform
        const float* __restrict__ wp = packed + u * PACK_STRIDE;
        float x1v[BASE], x2v[BASE], acc[BASE];
        #pragma unroll
        for (int i = 0; i < BASE; ++i) {
            x2v[i] = r2[u * BASE + i];      // per-lane gather, L2/L3-resident
            x1v[i] = lrow[u * BASE + i];    // ds_read, conflict-free (LSTR=289)
            acc[i] = 0.0f;
        }
        #pragma unroll
        for (int p = 0; p < NPATH; ++p) {
            #pragma unroll
            for (int i = 0; i < p_d1[p]; ++i) {
                #pragma unroll
                for (int j = 0; j < p_d2[p]; ++j) {
                    float xx = x1v[p_o1[p] + i] * x2v[p_o2[p] + j];
                    #pragma unroll
                    for (int k = 0; k < p_d3[p]; ++k) {
                        float w = wp[voloff[p] + (i * p_d2[p] + j) * p_d3[p] + k];
                        acc[p_o3[p] + k] = fmaf(w, xx, acc[p_o3[p] + k]);
                    }
                }
            }
        }
        if (vld) {
            #pragma unroll
            for (int k = 0; k < BASE; ++k) ro[u * BASE + k] = acc[k];
        }
    }
}

extern "C" void kernel_launch(void* const* d_in, const int* in_sizes, int n_in,
                              void* d_out, int out_size, void* d_ws, size_t ws_size,
                              hipStream_t stream) {
    const float* x1      = (const float*)d_in[0];
    const float* x2      = (const float*)d_in[1];
    const int*   idxs    = (const int*)d_in[2];
    const float* weights = (const float*)d_in[3];
    const float* w3j     = (const float*)d_in[4];
    const int*   dN      = (const int*)d_in[5];
    float* out = (float*)d_out;
    float* ws  = (float*)d_ws;

    const int E = in_sizes[2];
    const int eb = (E + 255) / 256;

    // CSR build: count -> scan -> bucket fill
    zero_count_kernel<<<256, 256, 0, stream>>>(ws, dN);
    hist_kernel<<<eb, 256, 0, stream>>>(idxs, ws, dN, E);
    scan_kernel<<<1, 1024, 0, stream>>>(ws, dN);
    fill_kernel<<<eb, 256, 0, stream>>>(idxs, ws, dN, E);

    // per-node gather-sum
    gather_sum_kernel<<<2048, 256, 0, stream>>>(x2, ws, dN);

    // packed per-u coefficients
    ww_build_kernel<<<MULV, 256, 0, stream>>>(weights, w3j, ws);

    // contraction: block-tiled, LDS-staged x1, wave-uniform u
    contract_kernel<<<(E + TILE - 1) / TILE, 256, 0, stream>>>(x1, idxs, ws, out, E);
}

// Round 5
// 339.140 us; speedup vs baseline: 1.3411x; 1.3411x over previous
//
#include <hip/hip_runtime.h>

#define MULV 32
#define BASE 9
#define ROW 288          // MULV*BASE
#define NPATH 11
#define W3J_SZ 729       // 9*9*9
#define PACK_STRIDE 384  // 363 packed coeffs per u, padded
#define PACK_TOTAL (MULV * PACK_STRIDE)   // 12288 floats
#define TILE 64          // edges per block in contract
#define CH 36            // floats per row per u-chunk (4 u's x 9)
#define LSTR 37          // LDS row stride: bank stride 5 (coprime 32) -> conflict-free b32

// Path table: (i1,i2,io) blocks for IRREPS [(0,e),(1,o),(2,e)], dims {1,3,5}, offs {0,1,4}
// Blocks are disjoint cells of the 9x9x9 cube; values read from input w3j at runtime.
__device__ constexpr int p_o1[NPATH] = {0,1,4, 0,1,1,4, 0,1,4,4};
__device__ constexpr int p_d1[NPATH] = {1,3,5, 1,3,3,5, 1,3,5,5};
__device__ constexpr int p_o2[NPATH] = {0,1,4, 1,0,4,1, 4,1,0,4};
__device__ constexpr int p_d2[NPATH] = {1,3,5, 3,1,5,3, 5,3,1,5};
__device__ constexpr int p_o3[NPATH] = {0,0,0, 1,1,1,1, 4,4,4,4};
__device__ constexpr int p_d3[NPATH] = {1,1,1, 3,3,3,3, 5,5,5,5};
__device__ constexpr int voloff[NPATH + 1] = {0,1,10,35,44,53,98,143,168,213,238,363};

// ---- ws layout ----
// packed : ws[0 .. PACK_TOTAL)
// x2s    : ws + PACK_TOTAL, N*ROW floats
// count  : (int*) after x2s, N ints
// offset : count + N ; cursor : count + 2N ; bucket : count + 3N (E ints)

__global__ void zero_count_kernel(float* __restrict__ ws, const int* __restrict__ dN) {
    int N = dN[0];
    int* count = (int*)(ws + PACK_TOTAL + (long)N * ROW);
    for (int i = blockIdx.x * blockDim.x + threadIdx.x; i < N; i += gridDim.x * blockDim.x)
        count[i] = 0;
}

__global__ void hist_kernel(const int* __restrict__ idxs, float* __restrict__ ws,
                            const int* __restrict__ dN, int E) {
    int N = dN[0];
    int* count = (int*)(ws + PACK_TOTAL + (long)N * ROW);
    int t = blockIdx.x * blockDim.x + threadIdx.x;
    if (t < E) atomicAdd(&count[idxs[t]], 1);
}

// single-block exclusive scan: offset[i] = sum count[0..i); also copy to cursor
__global__ void scan_kernel(float* __restrict__ ws, const int* __restrict__ dN) {
    int N = dN[0];
    int* count  = (int*)(ws + PACK_TOTAL + (long)N * ROW);
    int* offset = count + N;
    int* cursor = count + 2 * N;
    __shared__ int buf[1024];
    __shared__ int carry_s;
    if (threadIdx.x == 0) carry_s = 0;
    __syncthreads();
    for (int base = 0; base < N; base += 1024) {
        int i = base + (int)threadIdx.x;
        int v = (i < N) ? count[i] : 0;
        buf[threadIdx.x] = v;
        __syncthreads();
        #pragma unroll
        for (int off = 1; off < 1024; off <<= 1) {
            int t = (threadIdx.x >= off) ? buf[threadIdx.x - off] : 0;
            __syncthreads();
            buf[threadIdx.x] += t;
            __syncthreads();
        }
        int excl = carry_s + buf[threadIdx.x] - v;
        if (i < N) { offset[i] = excl; cursor[i] = excl; }
        __syncthreads();
        if (threadIdx.x == 0) carry_s += buf[1023];
        __syncthreads();
    }
}

__global__ void fill_kernel(const int* __restrict__ idxs, float* __restrict__ ws,
                            const int* __restrict__ dN, int E) {
    int N = dN[0];
    int* count  = (int*)(ws + PACK_TOTAL + (long)N * ROW);
    int* cursor = count + 2 * N;
    int* bucket = count + 3 * N;
    int t = blockIdx.x * blockDim.x + threadIdx.x;
    if (t < E) {
        int n = idxs[t];
        int pos = atomicAdd(&cursor[n], 1);
        bucket[pos] = t;
    }
}

// one wave per node: x2s[n,:] = sum over edges in bucket of x2[e,:]
__global__ __launch_bounds__(256) void gather_sum_kernel(const float* __restrict__ x2,
                                                         float* __restrict__ ws,
                                                         const int* __restrict__ dN) {
    int N = dN[0];
    float* x2s  = ws + PACK_TOTAL;
    int* count  = (int*)(x2s + (long)N * ROW);
    int* offset = count + N;
    int* bucket = count + 3 * N;
    const int lane = threadIdx.x & 63;
    const int wv   = threadIdx.x >> 6;
    for (int n0 = blockIdx.x * 4 + wv; n0 < N; n0 += gridDim.x * 4) {
        int n   = __builtin_amdgcn_readfirstlane(n0);
        int off = offset[n];
        int deg = count[n];
        float4 a0 = make_float4(0.f, 0.f, 0.f, 0.f);
        float4 a1 = make_float4(0.f, 0.f, 0.f, 0.f);
        for (int d = 0; d < deg; ++d) {
            int e = bucket[off + d];
            const float4* row = (const float4*)(x2 + (long)e * ROW);
            float4 v = row[lane];
            a0.x += v.x; a0.y += v.y; a0.z += v.z; a0.w += v.w;
            if (lane < 8) {
                float4 w = row[64 + lane];
                a1.x += w.x; a1.y += w.y; a1.z += w.z; a1.w += w.w;
            }
        }
        float4* orow = (float4*)(x2s + (long)n * ROW);
        orow[lane] = a0;
        if (lane < 8) orow[64 + lane] = a1;
    }
}

// packed[u][pos] = weights[u,p] * w3j[p, cell(pos)]
__global__ void ww_build_kernel(const float* __restrict__ weights,
                                const float* __restrict__ w3j,
                                float* __restrict__ packed) {
    int u = blockIdx.x;
    for (int t = threadIdx.x; t < 363; t += blockDim.x) {
        int p = 0;
        while (t >= voloff[p + 1]) ++p;
        int local = t - voloff[p];
        int d2 = p_d2[p], d3 = p_d3[p];
        int k = local % d3;
        int j = (local / d3) % d2;
        int i = local / (d3 * d2);
        int idx = (p_o1[p] + i) * 81 + (p_o2[p] + j) * 9 + (p_o3[p] + k);
        packed[u * PACK_STRIDE + t] = weights[u * NPATH + p] * w3j[p * W3J_SZ + idx];
    }
}

// Block = 256 threads = 4 waves, 64 edges. u-chunked: chunk uu covers u = uu*4 + wv
// (wave-uniform u -> coeffs via s_load). Per chunk only columns [uu*36, uu*36+36) of
// each row are touched: staged through LDS with coalesced float4 global access on both
// read (x1) and write (out) sides -> full-line HBM transactions.
__global__ __launch_bounds__(256, 8) void contract_kernel(
    const float* __restrict__ x1, const int* __restrict__ idxs,
    const float* __restrict__ ws, float* __restrict__ out, int E)
{
    __shared__ float lx1[TILE * LSTR];
    __shared__ float lout[TILE * LSTR];
    const int tid = threadIdx.x;
    const long ebase = (long)blockIdx.x * TILE;
    const float* __restrict__ packed = ws;
    const float* __restrict__ x2s    = ws + PACK_TOTAL;

    const int lane = tid & 63;
    const int wv   = __builtin_amdgcn_readfirstlane(tid >> 6);
    const long e   = ebase + lane;
    const bool vld = (e < (long)E);
    const int n = idxs[vld ? e : 0];
    const float* __restrict__ r2 = x2s + (long)n * ROW;

    #pragma unroll 1
    for (int uu = 0; uu < MULV / 4; ++uu) {
        const int u = (uu << 2) + wv;                    // wave-uniform
        const float* __restrict__ wp = packed + u * PACK_STRIDE;

        // stage x1 column-slice [uu*36, uu*36+36) of 64 rows: 576 float4s
        for (int q = tid; q < TILE * (CH / 4); q += 256) {
            int r = q / (CH / 4);
            int c = q - r * (CH / 4);
            long er = ebase + r;
            if (er < (long)E) {
                float4 v = *(const float4*)(x1 + er * ROW + uu * CH + c * 4);
                float* d = &lx1[r * LSTR + c * 4];
                d[0] = v.x; d[1] = v.y; d[2] = v.z; d[3] = v.w;
            }
        }
        __syncthreads();

        float x1v[BASE], x2v[BASE], acc[BASE];
        #pragma unroll
        for (int i = 0; i < BASE; ++i) {
            x2v[i] = r2[u * BASE + i];                    // per-lane, L2/L3-resident
            x1v[i] = lx1[lane * LSTR + wv * BASE + i];    // conflict-free b32
            acc[i] = 0.0f;
        }
        #pragma unroll
        for (int p = 0; p < NPATH; ++p) {
            #pragma unroll
            for (int i = 0; i < p_d1[p]; ++i) {
                #pragma unroll
                for (int j = 0; j < p_d2[p]; ++j) {
                    float xx = x1v[p_o1[p] + i] * x2v[p_o2[p] + j];
                    #pragma unroll
                    for (int k = 0; k < p_d3[p]; ++k) {
                        float w = wp[voloff[p] + (i * p_d2[p] + j) * p_d3[p] + k];
                        acc[p_o3[p] + k] = fmaf(w, xx, acc[p_o3[p] + k]);
                    }
                }
            }
        }
        #pragma unroll
        for (int k = 0; k < BASE; ++k)
            lout[lane * LSTR + wv * BASE + k] = acc[k];
        __syncthreads();

        // write out column-slice, coalesced float4
        for (int q = tid; q < TILE * (CH / 4); q += 256) {
            int r = q / (CH / 4);
            int c = q - r * (CH / 4);
            long er = ebase + r;
            if (er < (long)E) {
                const float* s = &lout[r * LSTR + c * 4];
                float4 v = make_float4(s[0], s[1], s[2], s[3]);
                *(float4*)(out + er * ROW + uu * CH + c * 4) = v;
            }
        }
        __syncthreads();   // protect lx1/lout before next chunk overwrites
    }
}

extern "C" void kernel_launch(void* const* d_in, const int* in_sizes, int n_in,
                              void* d_out, int out_size, void* d_ws, size_t ws_size,
                              hipStream_t stream) {
    const float* x1      = (const float*)d_in[0];
    const float* x2      = (const float*)d_in[1];
    const int*   idxs    = (const int*)d_in[2];
    const float* weights = (const float*)d_in[3];
    const float* w3j     = (const float*)d_in[4];
    const int*   dN      = (const int*)d_in[5];
    float* out = (float*)d_out;
    float* ws  = (float*)d_ws;

    const int E = in_sizes[2];
    const int eb = (E + 255) / 256;

    // CSR build: count -> scan -> bucket fill
    zero_count_kernel<<<256, 256, 0, stream>>>(ws, dN);
    hist_kernel<<<eb, 256, 0, stream>>>(idxs, ws, dN, E);
    scan_kernel<<<1, 1024, 0, stream>>>(ws, dN);
    fill_kernel<<<eb, 256, 0, stream>>>(idxs, ws, dN, E);

    // per-node gather-sum
    gather_sum_kernel<<<2048, 256, 0, stream>>>(x2, ws, dN);

    // packed per-u coefficients
    ww_build_kernel<<<MULV, 256, 0, stream>>>(weights, w3j, ws);

    // contraction: u-chunked, LDS-staged slices, wave-uniform u
    contract_kernel<<<(E + TILE - 1) / TILE, 256, 0, stream>>>(x1, idxs, ws, out, E);
}

// Round 6
// 327.050 us; speedup vs baseline: 1.3907x; 1.0370x over previous
//
#include <hip/hip_runtime.h>

#define MULV 32
#define BASE 9
#define ROW 288          // MULV*BASE
#define NPATH 11
#define W3J_SZ 729       // 9*9*9
#define PACK_STRIDE 384  // 363 packed coeffs per u, padded
#define PACK_TOTAL (MULV * PACK_STRIDE)   // 12288 floats
#define TILE 64          // edges per block in contract (lane <-> edge)
#define LSTR 289         // LDS row stride: bank stride 1 -> conflict-free b32 compute reads

// Path table: (i1,i2,io) blocks for IRREPS [(0,e),(1,o),(2,e)], dims {1,3,5}, offs {0,1,4}
// Blocks are disjoint cells of the 9x9x9 cube; values read from input w3j at runtime.
__device__ constexpr int p_o1[NPATH] = {0,1,4, 0,1,1,4, 0,1,4,4};
__device__ constexpr int p_d1[NPATH] = {1,3,5, 1,3,3,5, 1,3,5,5};
__device__ constexpr int p_o2[NPATH] = {0,1,4, 1,0,4,1, 4,1,0,4};
__device__ constexpr int p_d2[NPATH] = {1,3,5, 3,1,5,3, 5,3,1,5};
__device__ constexpr int p_o3[NPATH] = {0,0,0, 1,1,1,1, 4,4,4,4};
__device__ constexpr int p_d3[NPATH] = {1,1,1, 3,3,3,3, 5,5,5,5};
__device__ constexpr int voloff[NPATH + 1] = {0,1,10,35,44,53,98,143,168,213,238,363};

// ---- ws layout ----
// packed : ws[0 .. PACK_TOTAL)
// x2s    : ws + PACK_TOTAL, N*ROW floats
// count  : (int*) after x2s, N ints
// offset : count + N ; cursor : count + 2N ; bucket : count + 3N (E ints)

__global__ void zero_count_kernel(float* __restrict__ ws, const int* __restrict__ dN) {
    int N = dN[0];
    int* count = (int*)(ws + PACK_TOTAL + (long)N * ROW);
    for (int i = blockIdx.x * blockDim.x + threadIdx.x; i < N; i += gridDim.x * blockDim.x)
        count[i] = 0;
}

__global__ void hist_kernel(const int* __restrict__ idxs, float* __restrict__ ws,
                            const int* __restrict__ dN, int E) {
    int N = dN[0];
    int* count = (int*)(ws + PACK_TOTAL + (long)N * ROW);
    int t = blockIdx.x * blockDim.x + threadIdx.x;
    if (t < E) atomicAdd(&count[idxs[t]], 1);
}

// single block: per-thread serial prefix over ~N/256 elems + one 256-wide scan
__global__ void scan_kernel(float* __restrict__ ws, const int* __restrict__ dN) {
    int N = dN[0];
    int* count  = (int*)(ws + PACK_TOTAL + (long)N * ROW);
    int* offset = count + N;
    int* cursor = count + 2 * N;
    __shared__ int tsum[256];
    const int tid = threadIdx.x;
    int cpt = (N + 255) / 256;
    int lo = tid * cpt;
    int hi = lo + cpt; if (hi > N) hi = N;
    int s = 0;
    for (int i = lo; i < hi; ++i) s += count[i];
    int v = s;
    tsum[tid] = v;
    __syncthreads();
    #pragma unroll
    for (int off = 1; off < 256; off <<= 1) {
        int t = (tid >= off) ? tsum[tid - off] : 0;
        __syncthreads();
        v += t;
        tsum[tid] = v;
        __syncthreads();
    }
    int run = v - s;   // exclusive base for this thread's range
    for (int i = lo; i < hi; ++i) {
        int c = count[i];
        offset[i] = run; cursor[i] = run;
        run += c;
    }
}

__global__ void fill_kernel(const int* __restrict__ idxs, float* __restrict__ ws,
                            const int* __restrict__ dN, int E) {
    int N = dN[0];
    int* count  = (int*)(ws + PACK_TOTAL + (long)N * ROW);
    int* cursor = count + 2 * N;
    int* bucket = count + 3 * N;
    int t = blockIdx.x * blockDim.x + threadIdx.x;
    if (t < E) {
        int n = idxs[t];
        int pos = atomicAdd(&cursor[n], 1);
        bucket[pos] = t;
    }
}

// one wave per node: x2s[n,:] = sum over edges in bucket of x2[e,:]
__global__ __launch_bounds__(256) void gather_sum_kernel(const float* __restrict__ x2,
                                                         float* __restrict__ ws,
                                                         const int* __restrict__ dN) {
    int N = dN[0];
    float* x2s  = ws + PACK_TOTAL;
    int* count  = (int*)(x2s + (long)N * ROW);
    int* offset = count + N;
    int* bucket = count + 3 * N;
    const int lane = threadIdx.x & 63;
    const int wv   = threadIdx.x >> 6;
    for (int n0 = blockIdx.x * 4 + wv; n0 < N; n0 += gridDim.x * 4) {
        int n   = __builtin_amdgcn_readfirstlane(n0);
        int off = offset[n];
        int deg = count[n];
        float4 a0 = make_float4(0.f, 0.f, 0.f, 0.f);
        float4 a1 = make_float4(0.f, 0.f, 0.f, 0.f);
        for (int d = 0; d < deg; ++d) {
            int e = bucket[off + d];
            const float4* row = (const float4*)(x2 + (long)e * ROW);
            float4 v = row[lane];
            a0.x += v.x; a0.y += v.y; a0.z += v.z; a0.w += v.w;
            if (lane < 8) {
                float4 w = row[64 + lane];
                a1.x += w.x; a1.y += w.y; a1.z += w.z; a1.w += w.w;
            }
        }
        float4* orow = (float4*)(x2s + (long)n * ROW);
        orow[lane] = a0;
        if (lane < 8) orow[64 + lane] = a1;
    }
}

// packed[u][pos] = weights[u,p] * w3j[p, cell(pos)]
__global__ void ww_build_kernel(const float* __restrict__ weights,
                                const float* __restrict__ w3j,
                                float* __restrict__ packed) {
    int u = blockIdx.x;
    for (int t = threadIdx.x; t < 363; t += blockDim.x) {
        int p = 0;
        while (t >= voloff[p + 1]) ++p;
        int local = t - voloff[p];
        int d2 = p_d2[p], d3 = p_d3[p];
        int k = local % d3;
        int j = (local / d3) % d2;
        int i = local / (d3 * d2);
        int idx = (p_o1[p] + i) * 81 + (p_o2[p] + j) * 9 + (p_o3[p] + k);
        packed[u * PACK_STRIDE + t] = weights[u * NPATH + p] * w3j[p * W3J_SZ + idx];
    }
}

// Block = 256 threads = 4 waves, 64 edges (lane <-> edge). Full x1 tile staged in LDS.
// Chunk uu: u = uu*4 + wv (wave-uniform -> coeffs via s_load). Each (lane,wave) reads
// exactly the 9 LDS floats it overwrites with its acc -> NO barriers in the chunk loop;
// LDS morphs in place from x1 tile to out tile. One coalesced float4 write at the end:
// every out line written once, fully -> no fetch-for-write, no write amplification.
__global__ __launch_bounds__(256, 2) void contract_kernel(
    const float* __restrict__ x1, const int* __restrict__ idxs,
    const float* __restrict__ ws, float* __restrict__ out, int E)
{
    __shared__ float tile[TILE * LSTR];   // 73.98 KB -> 2 blocks/CU
    const int tid = threadIdx.x;
    const long ebase = (long)blockIdx.x * TILE;
    const float* __restrict__ packed = ws;
    const float* __restrict__ x2s    = ws + PACK_TOTAL;

    // stage full x1 tile: 64 rows x 72 float4, coalesced
    for (int q = tid; q < TILE * (ROW / 4); q += 256) {
        int r = q / (ROW / 4);
        int c = q - r * (ROW / 4);
        long er = ebase + r;
        if (er < (long)E) {
            float4 v = *(const float4*)(x1 + er * ROW + c * 4);
            float* d = &tile[r * LSTR + c * 4];
            d[0] = v.x; d[1] = v.y; d[2] = v.z; d[3] = v.w;
        }
    }
    __syncthreads();

    const int lane = tid & 63;
    const int wv   = __builtin_amdgcn_readfirstlane(tid >> 6);
    const long e   = ebase + lane;
    const bool vld = (e < (long)E);
    const int n = idxs[vld ? e : 0];
    const float* __restrict__ r2 = x2s + (long)n * ROW;
    float* __restrict__ lrow = &tile[lane * LSTR];

    // prefetch chunk 0's x2 slice
    float x2c[BASE];
    #pragma unroll
    for (int i = 0; i < BASE; ++i) x2c[i] = r2[wv * BASE + i];

    #pragma unroll 1
    for (int uu = 0; uu < MULV / 4; ++uu) {
        const int u = (uu << 2) + wv;                 // wave-uniform
        const float* __restrict__ wp = packed + u * PACK_STRIDE;

        float x2n[BASE];
        if (uu < MULV / 4 - 1) {
            #pragma unroll
            for (int i = 0; i < BASE; ++i) x2n[i] = r2[(u + 4) * BASE + i];
        }

        float x1v[BASE], acc[BASE];
        #pragma unroll
        for (int i = 0; i < BASE; ++i) {
            x1v[i] = lrow[u * BASE + i];              // conflict-free b32 (LSTR=289)
            acc[i] = 0.0f;
        }
        #pragma unroll
        for (int p = 0; p < NPATH; ++p) {
            #pragma unroll
            for (int i = 0; i < p_d1[p]; ++i) {
                #pragma unroll
                for (int j = 0; j < p_d2[p]; ++j) {
                    float xx = x1v[p_o1[p] + i] * x2c[p_o2[p] + j];
                    #pragma unroll
                    for (int k = 0; k < p_d3[p]; ++k) {
                        float w = wp[voloff[p] + (i * p_d2[p] + j) * p_d3[p] + k];
                        acc[p_o3[p] + k] = fmaf(w, xx, acc[p_o3[p] + k]);
                    }
                }
            }
        }
        #pragma unroll
        for (int k = 0; k < BASE; ++k)
            lrow[u * BASE + k] = acc[k];              // overwrite own x1 slice in place
        if (uu < MULV / 4 - 1) {
            #pragma unroll
            for (int i = 0; i < BASE; ++i) x2c[i] = x2n[i];
        }
    }
    __syncthreads();

    // write full rows, coalesced float4 -> full 128B lines, written exactly once
    for (int q = tid; q < TILE * (ROW / 4); q += 256) {
        int r = q / (ROW / 4);
        int c = q - r * (ROW / 4);
        long er = ebase + r;
        if (er < (long)E) {
            const float* s = &tile[r * LSTR + c * 4];
            *(float4*)(out + er * ROW + c * 4) = make_float4(s[0], s[1], s[2], s[3]);
        }
    }
}

extern "C" void kernel_launch(void* const* d_in, const int* in_sizes, int n_in,
                              void* d_out, int out_size, void* d_ws, size_t ws_size,
                              hipStream_t stream) {
    const float* x1      = (const float*)d_in[0];
    const float* x2      = (const float*)d_in[1];
    const int*   idxs    = (const int*)d_in[2];
    const float* weights = (const float*)d_in[3];
    const float* w3j     = (const float*)d_in[4];
    const int*   dN      = (const int*)d_in[5];
    float* out = (float*)d_out;
    float* ws  = (float*)d_ws;

    const int E = in_sizes[2];
    const int eb = (E + 255) / 256;

    // CSR build: count -> scan -> bucket fill
    zero_count_kernel<<<256, 256, 0, stream>>>(ws, dN);
    hist_kernel<<<eb, 256, 0, stream>>>(idxs, ws, dN, E);
    scan_kernel<<<1, 256, 0, stream>>>(ws, dN);
    fill_kernel<<<eb, 256, 0, stream>>>(idxs, ws, dN, E);

    // per-node gather-sum
    gather_sum_kernel<<<2048, 256, 0, stream>>>(x2, ws, dN);

    // packed per-u coefficients
    ww_build_kernel<<<MULV, 256, 0, stream>>>(weights, w3j, ws);

    // contraction: in-place LDS tile (x1 -> out), 2 barriers, coalesced IO
    contract_kernel<<<(E + TILE - 1) / TILE, 256, 0, stream>>>(x1, idxs, ws, out, E);
}

// Round 7
// 254.746 us; speedup vs baseline: 1.7855x; 1.2838x over previous
//
#include <hip/hip_runtime.h>

#define MULV 32
#define BASE 9
#define ROW 288          // MULV*BASE
#define NPATH 11
#define W3J_SZ 729       // 9*9*9
#define PACK_STRIDE 384  // 363 packed coeffs per u, padded
#define PACK_TOTAL (MULV * PACK_STRIDE)   // 12288 floats
#define TILE 64          // edges per block in contract (lane <-> edge)
#define HCOL 144         // columns per half-tile (16 u's x 9)
#define LSTR 145         // LDS row stride: bank stride 17 (coprime 32) -> conflict-free b32

// Path table: (i1,i2,io) blocks for IRREPS [(0,e),(1,o),(2,e)], dims {1,3,5}, offs {0,1,4}
// Blocks are disjoint cells of the 9x9x9 cube; values read from input w3j at runtime.
__device__ constexpr int p_o1[NPATH] = {0,1,4, 0,1,1,4, 0,1,4,4};
__device__ constexpr int p_d1[NPATH] = {1,3,5, 1,3,3,5, 1,3,5,5};
__device__ constexpr int p_o2[NPATH] = {0,1,4, 1,0,4,1, 4,1,0,4};
__device__ constexpr int p_d2[NPATH] = {1,3,5, 3,1,5,3, 5,3,1,5};
__device__ constexpr int p_o3[NPATH] = {0,0,0, 1,1,1,1, 4,4,4,4};
__device__ constexpr int p_d3[NPATH] = {1,1,1, 3,3,3,3, 5,5,5,5};
__device__ constexpr int voloff[NPATH + 1] = {0,1,10,35,44,53,98,143,168,213,238,363};

// ---- ws layout ----
// packed : ws[0 .. PACK_TOTAL)
// x2s    : ws + PACK_TOTAL, N*ROW floats
// count  : (int*) after x2s, N ints
// offset : count + N ; cursor : count + 2N ; bucket : count + 3N (E ints)

__global__ void zero_count_kernel(float* __restrict__ ws, const int* __restrict__ dN) {
    int N = dN[0];
    int* count = (int*)(ws + PACK_TOTAL + (long)N * ROW);
    for (int i = blockIdx.x * blockDim.x + threadIdx.x; i < N; i += gridDim.x * blockDim.x)
        count[i] = 0;
}

__global__ void hist_kernel(const int* __restrict__ idxs, float* __restrict__ ws,
                            const int* __restrict__ dN, int E) {
    int N = dN[0];
    int* count = (int*)(ws + PACK_TOTAL + (long)N * ROW);
    int t = blockIdx.x * blockDim.x + threadIdx.x;
    if (t < E) atomicAdd(&count[idxs[t]], 1);
}

// single block: per-thread serial prefix over ~N/256 elems + one 256-wide scan
__global__ void scan_kernel(float* __restrict__ ws, const int* __restrict__ dN) {
    int N = dN[0];
    int* count  = (int*)(ws + PACK_TOTAL + (long)N * ROW);
    int* offset = count + N;
    int* cursor = count + 2 * N;
    __shared__ int tsum[256];
    const int tid = threadIdx.x;
    int cpt = (N + 255) / 256;
    int lo = tid * cpt;
    int hi = lo + cpt; if (hi > N) hi = N;
    int s = 0;
    for (int i = lo; i < hi; ++i) s += count[i];
    int v = s;
    tsum[tid] = v;
    __syncthreads();
    #pragma unroll
    for (int off = 1; off < 256; off <<= 1) {
        int t = (tid >= off) ? tsum[tid - off] : 0;
        __syncthreads();
        v += t;
        tsum[tid] = v;
        __syncthreads();
    }
    int run = v - s;   // exclusive base for this thread's range
    for (int i = lo; i < hi; ++i) {
        int c = count[i];
        offset[i] = run; cursor[i] = run;
        run += c;
    }
}

__global__ void fill_kernel(const int* __restrict__ idxs, float* __restrict__ ws,
                            const int* __restrict__ dN, int E) {
    int N = dN[0];
    int* count  = (int*)(ws + PACK_TOTAL + (long)N * ROW);
    int* cursor = count + 2 * N;
    int* bucket = count + 3 * N;
    int t = blockIdx.x * blockDim.x + threadIdx.x;
    if (t < E) {
        int n = idxs[t];
        int pos = atomicAdd(&cursor[n], 1);
        bucket[pos] = t;
    }
}

// one wave per node: x2s[n,:] = sum over edges in bucket of x2[e,:]
__global__ __launch_bounds__(256) void gather_sum_kernel(const float* __restrict__ x2,
                                                         float* __restrict__ ws,
                                                         const int* __restrict__ dN) {
    int N = dN[0];
    float* x2s  = ws + PACK_TOTAL;
    int* count  = (int*)(x2s + (long)N * ROW);
    int* offset = count + N;
    int* bucket = count + 3 * N;
    const int lane = threadIdx.x & 63;
    const int wv   = threadIdx.x >> 6;
    for (int n0 = blockIdx.x * 4 + wv; n0 < N; n0 += gridDim.x * 4) {
        int n   = __builtin_amdgcn_readfirstlane(n0);
        int off = offset[n];
        int deg = count[n];
        float4 a0 = make_float4(0.f, 0.f, 0.f, 0.f);
        float4 a1 = make_float4(0.f, 0.f, 0.f, 0.f);
        for (int d = 0; d < deg; ++d) {
            int e = bucket[off + d];
            const float4* row = (const float4*)(x2 + (long)e * ROW);
            float4 v = row[lane];
            a0.x += v.x; a0.y += v.y; a0.z += v.z; a0.w += v.w;
            if (lane < 8) {
                float4 w = row[64 + lane];
                a1.x += w.x; a1.y += w.y; a1.z += w.z; a1.w += w.w;
            }
        }
        float4* orow = (float4*)(x2s + (long)n * ROW);
        orow[lane] = a0;
        if (lane < 8) orow[64 + lane] = a1;
    }
}

// packed[u][pos] = weights[u,p] * w3j[p, cell(pos)]
__global__ void ww_build_kernel(const float* __restrict__ weights,
                                const float* __restrict__ w3j,
                                float* __restrict__ packed) {
    int u = blockIdx.x;
    for (int t = threadIdx.x; t < 363; t += blockDim.x) {
        int p = 0;
        while (t >= voloff[p + 1]) ++p;
        int local = t - voloff[p];
        int d2 = p_d2[p], d3 = p_d3[p];
        int k = local % d3;
        int j = (local / d3) % d2;
        int i = local / (d3 * d2);
        int idx = (p_o1[p] + i) * 81 + (p_o2[p] + j) * 9 + (p_o3[p] + k);
        packed[u * PACK_STRIDE + t] = weights[u * NPATH + p] * w3j[p * W3J_SZ + idx];
    }
}

// Block = 256 threads = 4 waves, 64 edges (lane <-> edge). Two half-tiles of 144 cols
// (37.1 KB LDS -> 4 blocks/CU). Within a half: chunk uu covers u = uu*4 + wv
// (wave-uniform -> coeffs via s_load); each (lane,wv) reads exactly the 9 LDS words it
// overwrites with acc -> no barriers inside the chunk loop; LDS morphs x1 -> out in
// place. Coalesced float4 global IO on both sides; every out line written once, fully.
__global__ __launch_bounds__(256, 4) void contract_kernel(
    const float* __restrict__ x1, const int* __restrict__ idxs,
    const float* __restrict__ ws, float* __restrict__ out, int E)
{
    __shared__ float tile[TILE * LSTR];   // 37,120 B
    const int tid = threadIdx.x;
    const long ebase = (long)blockIdx.x * TILE;
    const float* __restrict__ packed = ws;
    const float* __restrict__ x2s    = ws + PACK_TOTAL;

    const int lane = tid & 63;
    const int wv   = __builtin_amdgcn_readfirstlane(tid >> 6);
    const long e   = ebase + lane;
    const bool vld = (e < (long)E);
    const int n = idxs[vld ? e : 0];
    const float* __restrict__ r2 = x2s + (long)n * ROW;
    float* __restrict__ lrow = &tile[lane * LSTR];

    // prefetch chunk 0's x2 slice
    float x2c[BASE];
    #pragma unroll
    for (int i = 0; i < BASE; ++i) x2c[i] = r2[wv * BASE + i];

    #pragma unroll 1
    for (int h = 0; h < 2; ++h) {
        // stage half-tile: 64 rows x 36 float4, coalesced
        for (int q = tid; q < TILE * (HCOL / 4); q += 256) {
            int r = q / (HCOL / 4);
            int c = q - r * (HCOL / 4);
            long er = ebase + r;
            if (er < (long)E) {
                float4 v = *(const float4*)(x1 + er * ROW + h * HCOL + c * 4);
                float* d = &tile[r * LSTR + c * 4];
                d[0] = v.x; d[1] = v.y; d[2] = v.z; d[3] = v.w;
            }
        }
        __syncthreads();

        #pragma unroll 1
        for (int uu = 4 * h; uu < 4 * h + 4; ++uu) {
            const int u = (uu << 2) + wv;                 // wave-uniform
            const float* __restrict__ wp = packed + u * PACK_STRIDE;

            float x2n[BASE];
            if (u + 4 < MULV) {
                #pragma unroll
                for (int i = 0; i < BASE; ++i) x2n[i] = r2[(u + 4) * BASE + i];
            }

            const int lbase = u * BASE - h * HCOL;        // offset within half-tile row
            float x1v[BASE], acc[BASE];
            #pragma unroll
            for (int i = 0; i < BASE; ++i) {
                x1v[i] = lrow[lbase + i];                 // conflict-free b32
                acc[i] = 0.0f;
            }
            #pragma unroll
            for (int p = 0; p < NPATH; ++p) {
                #pragma unroll
                for (int i = 0; i < p_d1[p]; ++i) {
                    #pragma unroll
                    for (int j = 0; j < p_d2[p]; ++j) {
                        float xx = x1v[p_o1[p] + i] * x2c[p_o2[p] + j];
                        #pragma unroll
                        for (int k = 0; k < p_d3[p]; ++k) {
                            float w = wp[voloff[p] + (i * p_d2[p] + j) * p_d3[p] + k];
                            acc[p_o3[p] + k] = fmaf(w, xx, acc[p_o3[p] + k]);
                        }
                    }
                }
            }
            #pragma unroll
            for (int k = 0; k < BASE; ++k)
                lrow[lbase + k] = acc[k];                 // overwrite own slice in place
            if (u + 4 < MULV) {
                #pragma unroll
                for (int i = 0; i < BASE; ++i) x2c[i] = x2n[i];
            }
        }
        __syncthreads();

        // write half-tile, coalesced float4 -> full lines written exactly once
        for (int q = tid; q < TILE * (HCOL / 4); q += 256) {
            int r = q / (HCOL / 4);
            int c = q - r * (HCOL / 4);
            long er = ebase + r;
            if (er < (long)E) {
                const float* s = &tile[r * LSTR + c * 4];
                *(float4*)(out + er * ROW + h * HCOL + c * 4) =
                    make_float4(s[0], s[1], s[2], s[3]);
            }
        }
        __syncthreads();   // protect tile before next half restages
    }
}

extern "C" void kernel_launch(void* const* d_in, const int* in_sizes, int n_in,
                              void* d_out, int out_size, void* d_ws, size_t ws_size,
                              hipStream_t stream) {
    const float* x1      = (const float*)d_in[0];
    const float* x2      = (const float*)d_in[1];
    const int*   idxs    = (const int*)d_in[2];
    const float* weights = (const float*)d_in[3];
    const float* w3j     = (const float*)d_in[4];
    const int*   dN      = (const int*)d_in[5];
    float* out = (float*)d_out;
    float* ws  = (float*)d_ws;

    const int E = in_sizes[2];
    const int eb = (E + 255) / 256;

    // CSR build: count -> scan -> bucket fill
    zero_count_kernel<<<256, 256, 0, stream>>>(ws, dN);
    hist_kernel<<<eb, 256, 0, stream>>>(idxs, ws, dN, E);
    scan_kernel<<<1, 256, 0, stream>>>(ws, dN);
    fill_kernel<<<eb, 256, 0, stream>>>(idxs, ws, dN, E);

    // per-node gather-sum
    gather_sum_kernel<<<2048, 256, 0, stream>>>(x2, ws, dN);

    // packed per-u coefficients
    ww_build_kernel<<<MULV, 256, 0, stream>>>(weights, w3j, ws);

    // contraction: two half-tiles, in-place LDS morph, 4 blocks/CU
    contract_kernel<<<(E + TILE - 1) / TILE, 256, 0, stream>>>(x1, idxs, ws, out, E);
}

// Round 8
// 213.251 us; speedup vs baseline: 2.1329x; 1.1946x over previous
//
#include <hip/hip_runtime.h>

#define MULV 32
#define BASE 9
#define ROW 288          // MULV*BASE
#define NPATH 11
#define W3J_SZ 729       // 9*9*9
#define PACK_STRIDE 96   // 83 nonzero packed coeffs per u, padded
#define PACK_TOTAL (MULV * PACK_STRIDE)
#define TILE 64          // edges per block (lane <-> edge)
#define QCOL 72          // columns per quarter-tile (8 u's x 9)
#define LSTR 73          // LDS row stride: bank stride 9 (coprime 32) -> conflict-free b32

// Path table: (i1,i2,io) blocks for IRREPS [(0,e),(1,o),(2,e)], dims {1,3,5}, offs {0,1,4}
// Blocks are disjoint cells of the 9x9x9 cube; values read from input w3j at runtime.
__device__ constexpr int p_o1[NPATH] = {0,1,4, 0,1,1,4, 0,1,4,4};
__device__ constexpr int p_d1[NPATH] = {1,3,5, 1,3,3,5, 1,3,5,5};
__device__ constexpr int p_o2[NPATH] = {0,1,4, 1,0,4,1, 4,1,0,4};
__device__ constexpr int p_d2[NPATH] = {1,3,5, 3,1,5,3, 5,3,1,5};
__device__ constexpr int p_o3[NPATH] = {0,0,0, 1,1,1,1, 4,4,4,4};
__device__ constexpr int p_d3[NPATH] = {1,1,1, 3,3,3,3, 5,5,5,5};
__device__ constexpr int p_l1[NPATH] = {0,1,2, 0,1,1,2, 0,1,2,2};
__device__ constexpr int p_l2[NPATH] = {0,1,2, 1,0,2,1, 2,1,0,2};
__device__ constexpr int p_l3[NPATH] = {0,0,0, 1,1,1,1, 2,2,2,2};

// Wigner real-basis selection rules (all paths have even l1+l2+l3):
// nonzero only if #{m<0} even AND |m3| in {|m1|+|m2|, ||m1|-|m2||}.
// Necessary conditions only: a false-positive cell merely wastes an FMA on 0.0.
__device__ __host__ constexpr bool cell_nz(int p, int i, int j, int k) {
    int m1 = i - p_l1[p], m2 = j - p_l2[p], m3 = k - p_l3[p];
    if ((((m1 < 0) + (m2 < 0) + (m3 < 0)) & 1) != 0) return false;
    int a1 = m1 < 0 ? -m1 : m1, a2 = m2 < 0 ? -m2 : m2, a3 = m3 < 0 ? -m3 : m3;
    int d = a1 - a2; if (d < 0) d = -d;
    return (a3 == a1 + a2) || (a3 == d);
}
__device__ __host__ constexpr bool pair_nz(int p, int i, int j) {
    for (int k = 0; k < p_d3[p]; ++k) if (cell_nz(p, i, j, k)) return true;
    return false;
}

// ---- ws layout ----
// packed : ws[0 .. PACK_TOTAL)
// x2s    : ws + PACK_TOTAL, N*ROW floats
// count  : (int*) after x2s, N ints
// offset : count + N ; cursor : count + 2N ; bucket : count + 3N (E ints)

__global__ void zero_count_kernel(float* __restrict__ ws, const int* __restrict__ dN) {
    int N = dN[0];
    int* count = (int*)(ws + PACK_TOTAL + (long)N * ROW);
    for (int i = blockIdx.x * blockDim.x + threadIdx.x; i < N; i += gridDim.x * blockDim.x)
        count[i] = 0;
}

__global__ void hist_kernel(const int* __restrict__ idxs, float* __restrict__ ws,
                            const int* __restrict__ dN, int E) {
    int N = dN[0];
    int* count = (int*)(ws + PACK_TOTAL + (long)N * ROW);
    int t = blockIdx.x * blockDim.x + threadIdx.x;
    if (t < E) atomicAdd(&count[idxs[t]], 1);
}

// single block: per-thread serial prefix over ~N/256 elems + one 256-wide scan
__global__ void scan_kernel(float* __restrict__ ws, const int* __restrict__ dN) {
    int N = dN[0];
    int* count  = (int*)(ws + PACK_TOTAL + (long)N * ROW);
    int* offset = count + N;
    int* cursor = count + 2 * N;
    __shared__ int tsum[256];
    const int tid = threadIdx.x;
    int cpt = (N + 255) / 256;
    int lo = tid * cpt;
    int hi = lo + cpt; if (hi > N) hi = N;
    int s = 0;
    for (int i = lo; i < hi; ++i) s += count[i];
    int v = s;
    tsum[tid] = v;
    __syncthreads();
    #pragma unroll
    for (int off = 1; off < 256; off <<= 1) {
        int t = (tid >= off) ? tsum[tid - off] : 0;
        __syncthreads();
        v += t;
        tsum[tid] = v;
        __syncthreads();
    }
    int run = v - s;
    for (int i = lo; i < hi; ++i) {
        int c = count[i];
        offset[i] = run; cursor[i] = run;
        run += c;
    }
}

__global__ void fill_kernel(const int* __restrict__ idxs, float* __restrict__ ws,
                            const int* __restrict__ dN, int E) {
    int N = dN[0];
    int* count  = (int*)(ws + PACK_TOTAL + (long)N * ROW);
    int* cursor = count + 2 * N;
    int* bucket = count + 3 * N;
    int t = blockIdx.x * blockDim.x + threadIdx.x;
    if (t < E) {
        int n = idxs[t];
        int pos = atomicAdd(&cursor[n], 1);
        bucket[pos] = t;
    }
}

// one wave per node: x2s[n,:] = sum over edges in bucket of x2[e,:]
__global__ __launch_bounds__(256) void gather_sum_kernel(const float* __restrict__ x2,
                                                         float* __restrict__ ws,
                                                         const int* __restrict__ dN) {
    int N = dN[0];
    float* x2s  = ws + PACK_TOTAL;
    int* count  = (int*)(x2s + (long)N * ROW);
    int* offset = count + N;
    int* bucket = count + 3 * N;
    const int lane = threadIdx.x & 63;
    const int wv   = threadIdx.x >> 6;
    for (int n0 = blockIdx.x * 4 + wv; n0 < N; n0 += gridDim.x * 4) {
        int n   = __builtin_amdgcn_readfirstlane(n0);
        int off = offset[n];
        int deg = count[n];
        float4 a0 = make_float4(0.f, 0.f, 0.f, 0.f);
        float4 a1 = make_float4(0.f, 0.f, 0.f, 0.f);
        for (int d = 0; d < deg; ++d) {
            int e = bucket[off + d];
            const float4* row = (const float4*)(x2 + (long)e * ROW);
            float4 v = row[lane];
            a0.x += v.x; a0.y += v.y; a0.z += v.z; a0.w += v.w;
            if (lane < 8) {
                float4 w = row[64 + lane];
                a1.x += w.x; a1.y += w.y; a1.z += w.z; a1.w += w.w;
            }
        }
        float4* orow = (float4*)(x2s + (long)n * ROW);
        orow[lane] = a0;
        if (lane < 8) orow[64 + lane] = a1;
    }
}

// packed[u][ci] = weights[u,p] * w3j[p, cell] over nonzero cells in fixed loop order
__global__ void ww_build_kernel(const float* __restrict__ weights,
                                const float* __restrict__ w3j,
                                float* __restrict__ packed) {
    int u = threadIdx.x;
    if (u >= MULV) return;
    int ci = 0;
    #pragma unroll
    for (int p = 0; p < NPATH; ++p) {
        float wgt = weights[u * NPATH + p];
        #pragma unroll
        for (int i = 0; i < p_d1[p]; ++i)
            #pragma unroll
            for (int j = 0; j < p_d2[p]; ++j)
                #pragma unroll
                for (int k = 0; k < p_d3[p]; ++k)
                    if (cell_nz(p, i, j, k)) {
                        int idx = (p_o1[p] + i) * 81 + (p_o2[p] + j) * 9 + (p_o3[p] + k);
                        packed[u * PACK_STRIDE + ci] = wgt * w3j[p * W3J_SZ + idx];
                        ++ci;
                    }
    }
}

// Block = 256 threads = 4 waves, 64 edges. Four quarter-tiles of 72 cols (18.7 KB LDS
// -> 8 blocks/CU). Quarter h covers u in [8h, 8h+8); chunk cc: u = 8h + cc*4 + wv
// (wave-uniform -> coeffs via s_load). Each (lane,wv,cc) reads exactly the 9 LDS words
// it overwrites -> no barrier between the 2 chunks; LDS morphs x1 -> out in place.
// Compile-time Wigner sparsity: 83 FMA + ~81 mul per chunk instead of 363+121.
__global__ __launch_bounds__(256, 8) void contract_kernel(
    const float* __restrict__ x1, const int* __restrict__ idxs,
    const float* __restrict__ ws, float* __restrict__ out, int E)
{
    __shared__ float tile[TILE * LSTR];   // 18,688 B
    const int tid = threadIdx.x;
    const long ebase = (long)blockIdx.x * TILE;
    const float* __restrict__ packed = ws;
    const float* __restrict__ x2s    = ws + PACK_TOTAL;

    const int lane = tid & 63;
    const int wv   = __builtin_amdgcn_readfirstlane(tid >> 6);
    const long e   = ebase + lane;
    const bool vld = (e < (long)E);
    const int n = idxs[vld ? e : 0];
    const float* __restrict__ r2 = x2s + (long)n * ROW;
    float* __restrict__ lrow = &tile[lane * LSTR];

    // prefetch chunk 0's x2 slice (u = wv)
    float x2c[BASE];
    #pragma unroll
    for (int i = 0; i < BASE; ++i) x2c[i] = r2[wv * BASE + i];

    #pragma unroll 1
    for (int h = 0; h < 4; ++h) {
        // stage quarter-tile: 64 rows x 18 float4, coalesced
        for (int q = tid; q < TILE * (QCOL / 4); q += 256) {
            int r = q / (QCOL / 4);
            int c = q - r * (QCOL / 4);
            long er = ebase + r;
            if (er < (long)E) {
                float4 v = *(const float4*)(x1 + er * ROW + h * QCOL + c * 4);
                float* d = &tile[r * LSTR + c * 4];
                d[0] = v.x; d[1] = v.y; d[2] = v.z; d[3] = v.w;
            }
        }
        __syncthreads();

        #pragma unroll 1
        for (int cc = 0; cc < 2; ++cc) {
            const int u = 8 * h + cc * 4 + wv;            // wave-uniform
            const float* __restrict__ wp = packed + u * PACK_STRIDE;

            float x2n[BASE];
            if (u + 4 < MULV) {
                #pragma unroll
                for (int i = 0; i < BASE; ++i) x2n[i] = r2[(u + 4) * BASE + i];
            }

            const int lbase = (cc * 4 + wv) * BASE;       // offset within quarter row
            float x1v[BASE], acc[BASE];
            #pragma unroll
            for (int i = 0; i < BASE; ++i) {
                x1v[i] = lrow[lbase + i];                 // conflict-free b32
                acc[i] = 0.0f;
            }

            int ci = 0;
            #pragma unroll
            for (int p = 0; p < NPATH; ++p) {
                #pragma unroll
                for (int i = 0; i < p_d1[p]; ++i) {
                    #pragma unroll
                    for (int j = 0; j < p_d2[p]; ++j) {
                        if (pair_nz(p, i, j)) {
                            float xx = x1v[p_o1[p] + i] * x2c[p_o2[p] + j];
                            #pragma unroll
                            for (int k = 0; k < p_d3[p]; ++k) {
                                if (cell_nz(p, i, j, k)) {
                                    acc[p_o3[p] + k] = fmaf(wp[ci], xx, acc[p_o3[p] + k]);
                                    ++ci;
                                }
                            }
                        }
                    }
                }
            }
            #pragma unroll
            for (int k = 0; k < BASE; ++k)
                lrow[lbase + k] = acc[k];                 // in-place overwrite
            if (u + 4 < MULV) {
                #pragma unroll
                for (int i = 0; i < BASE; ++i) x2c[i] = x2n[i];
            }
        }
        __syncthreads();

        // write quarter-tile, coalesced -> full lines written exactly once
        for (int q = tid; q < TILE * (QCOL / 4); q += 256) {
            int r = q / (QCOL / 4);
            int c = q - r * (QCOL / 4);
            long er = ebase + r;
            if (er < (long)E) {
                const float* s = &tile[r * LSTR + c * 4];
                *(float4*)(out + er * ROW + h * QCOL + c * 4) =
                    make_float4(s[0], s[1], s[2], s[3]);
            }
        }
        __syncthreads();
    }
}

extern "C" void kernel_launch(void* const* d_in, const int* in_sizes, int n_in,
                              void* d_out, int out_size, void* d_ws, size_t ws_size,
                              hipStream_t stream) {
    const float* x1      = (const float*)d_in[0];
    const float* x2      = (const float*)d_in[1];
    const int*   idxs    = (const int*)d_in[2];
    const float* weights = (const float*)d_in[3];
    const float* w3j     = (const float*)d_in[4];
    const int*   dN      = (const int*)d_in[5];
    float* out = (float*)d_out;
    float* ws  = (float*)d_ws;

    const int E = in_sizes[2];
    const int eb = (E + 255) / 256;

    // CSR build: count -> scan -> bucket fill
    zero_count_kernel<<<256, 256, 0, stream>>>(ws, dN);
    hist_kernel<<<eb, 256, 0, stream>>>(idxs, ws, dN, E);
    scan_kernel<<<1, 256, 0, stream>>>(ws, dN);
    fill_kernel<<<eb, 256, 0, stream>>>(idxs, ws, dN, E);

    // per-node gather-sum
    gather_sum_kernel<<<2048, 256, 0, stream>>>(x2, ws, dN);

    // packed per-u nonzero coefficients (83/u)
    ww_build_kernel<<<1, 64, 0, stream>>>(weights, w3j, ws);

    // contraction: quarter-tiles, in-place LDS morph, 8 blocks/CU, sparse FMAs
    contract_kernel<<<(E + TILE - 1) / TILE, 256, 0, stream>>>(x1, idxs, ws, out, E);
}

// Round 9
// 196.153 us; speedup vs baseline: 2.3188x; 1.0872x over previous
//
#include <hip/hip_runtime.h>

#define MULV 32
#define BASE 9
#define ROW 288          // MULV*BASE
#define NPATH 11
#define W3J_SZ 729       // 9*9*9
#define PACK_STRIDE 96   // 83 nonzero packed coeffs per u, padded
#define PACK_TOTAL (MULV * PACK_STRIDE)
#define TILE 64          // edges per block (lane <-> edge)
#define QCOL 72          // columns per quarter-tile (8 u's x 9)
#define LSTR 73          // LDS row stride: bank stride 9 (coprime 32) -> conflict-free b32

typedef float f4a4 __attribute__((ext_vector_type(4), aligned(4)));  // dword-aligned vec4 load

// Path table: (i1,i2,io) blocks for IRREPS [(0,e),(1,o),(2,e)], dims {1,3,5}, offs {0,1,4}
__device__ constexpr int p_o1[NPATH] = {0,1,4, 0,1,1,4, 0,1,4,4};
__device__ constexpr int p_d1[NPATH] = {1,3,5, 1,3,3,5, 1,3,5,5};
__device__ constexpr int p_o2[NPATH] = {0,1,4, 1,0,4,1, 4,1,0,4};
__device__ constexpr int p_d2[NPATH] = {1,3,5, 3,1,5,3, 5,3,1,5};
__device__ constexpr int p_o3[NPATH] = {0,0,0, 1,1,1,1, 4,4,4,4};
__device__ constexpr int p_d3[NPATH] = {1,1,1, 3,3,3,3, 5,5,5,5};
__device__ constexpr int p_l1[NPATH] = {0,1,2, 0,1,1,2, 0,1,2,2};
__device__ constexpr int p_l2[NPATH] = {0,1,2, 1,0,2,1, 2,1,0,2};
__device__ constexpr int p_l3[NPATH] = {0,0,0, 1,1,1,1, 2,2,2,2};

// Wigner real-basis selection rules (all paths have even l1+l2+l3):
// nonzero only if #{m<0} even AND |m3| in {|m1|+|m2|, ||m1|-|m2||}.
// Necessary conditions only: a false-positive cell merely wastes an FMA on 0.0.
__device__ __host__ constexpr bool cell_nz(int p, int i, int j, int k) {
    int m1 = i - p_l1[p], m2 = j - p_l2[p], m3 = k - p_l3[p];
    if ((((m1 < 0) + (m2 < 0) + (m3 < 0)) & 1) != 0) return false;
    int a1 = m1 < 0 ? -m1 : m1, a2 = m2 < 0 ? -m2 : m2, a3 = m3 < 0 ? -m3 : m3;
    int d = a1 - a2; if (d < 0) d = -d;
    return (a3 == a1 + a2) || (a3 == d);
}
__device__ __host__ constexpr bool pair_nz(int p, int i, int j) {
    for (int k = 0; k < p_d3[p]; ++k) if (cell_nz(p, i, j, k)) return true;
    return false;
}

// ---- ws layout ----
// packed : ws[0 .. PACK_TOTAL)
// x2s    : ws + PACK_TOTAL, N*ROW floats
// count  : (int*) after x2s, N ints
// offset : count + N ; cursor : count + 2N ; bucket : count + 3N (E ints)

__global__ void zero_count_kernel(float* __restrict__ ws, const int* __restrict__ dN) {
    int N = dN[0];
    int* count = (int*)(ws + PACK_TOTAL + (long)N * ROW);
    for (int i = blockIdx.x * blockDim.x + threadIdx.x; i < N; i += gridDim.x * blockDim.x)
        count[i] = 0;
}

__global__ void hist_kernel(const int* __restrict__ idxs, float* __restrict__ ws,
                            const int* __restrict__ dN, int E) {
    int N = dN[0];
    int* count = (int*)(ws + PACK_TOTAL + (long)N * ROW);
    int t = blockIdx.x * blockDim.x + threadIdx.x;
    if (t < E) atomicAdd(&count[idxs[t]], 1);
}

// single block: per-thread serial prefix over ~N/256 elems + one 256-wide scan
__global__ void scan_kernel(float* __restrict__ ws, const int* __restrict__ dN) {
    int N = dN[0];
    int* count  = (int*)(ws + PACK_TOTAL + (long)N * ROW);
    int* offset = count + N;
    int* cursor = count + 2 * N;
    __shared__ int tsum[256];
    const int tid = threadIdx.x;
    int cpt = (N + 255) / 256;
    int lo = tid * cpt;
    int hi = lo + cpt; if (hi > N) hi = N;
    int s = 0;
    for (int i = lo; i < hi; ++i) s += count[i];
    int v = s;
    tsum[tid] = v;
    __syncthreads();
    #pragma unroll
    for (int off = 1; off < 256; off <<= 1) {
        int t = (tid >= off) ? tsum[tid - off] : 0;
        __syncthreads();
        v += t;
        tsum[tid] = v;
        __syncthreads();
    }
    int run = v - s;
    for (int i = lo; i < hi; ++i) {
        int c = count[i];
        offset[i] = run; cursor[i] = run;
        run += c;
    }
}

__global__ void fill_kernel(const int* __restrict__ idxs, float* __restrict__ ws,
                            const int* __restrict__ dN, int E) {
    int N = dN[0];
    int* count  = (int*)(ws + PACK_TOTAL + (long)N * ROW);
    int* cursor = count + 2 * N;
    int* bucket = count + 3 * N;
    int t = blockIdx.x * blockDim.x + threadIdx.x;
    if (t < E) {
        int n = idxs[t];
        int pos = atomicAdd(&cursor[n], 1);
        bucket[pos] = t;
    }
}

// one wave per node: x2s[n,:] = sum over edges in bucket of x2[e,:]
__global__ __launch_bounds__(256) void gather_sum_kernel(const float* __restrict__ x2,
                                                         float* __restrict__ ws,
                                                         const int* __restrict__ dN) {
    int N = dN[0];
    float* x2s  = ws + PACK_TOTAL;
    int* count  = (int*)(x2s + (long)N * ROW);
    int* offset = count + N;
    int* bucket = count + 3 * N;
    const int lane = threadIdx.x & 63;
    const int wv   = threadIdx.x >> 6;
    for (int n0 = blockIdx.x * 4 + wv; n0 < N; n0 += gridDim.x * 4) {
        int n   = __builtin_amdgcn_readfirstlane(n0);
        int off = offset[n];
        int deg = count[n];
        float4 a0 = make_float4(0.f, 0.f, 0.f, 0.f);
        float4 a1 = make_float4(0.f, 0.f, 0.f, 0.f);
        for (int d = 0; d < deg; ++d) {
            int e = bucket[off + d];
            const float4* row = (const float4*)(x2 + (long)e * ROW);
            float4 v = row[lane];
            a0.x += v.x; a0.y += v.y; a0.z += v.z; a0.w += v.w;
            if (lane < 8) {
                float4 w = row[64 + lane];
                a1.x += w.x; a1.y += w.y; a1.z += w.z; a1.w += w.w;
            }
        }
        float4* orow = (float4*)(x2s + (long)n * ROW);
        orow[lane] = a0;
        if (lane < 8) orow[64 + lane] = a1;
    }
}

// packed[u][ci] = weights[u,p] * w3j[p, cell] over nonzero cells in fixed loop order
__global__ void ww_build_kernel(const float* __restrict__ weights,
                                const float* __restrict__ w3j,
                                float* __restrict__ packed) {
    int u = threadIdx.x;
    if (u >= MULV) return;
    int ci = 0;
    #pragma unroll
    for (int p = 0; p < NPATH; ++p) {
        float wgt = weights[u * NPATH + p];
        #pragma unroll
        for (int i = 0; i < p_d1[p]; ++i)
            #pragma unroll
            for (int j = 0; j < p_d2[p]; ++j)
                #pragma unroll
                for (int k = 0; k < p_d3[p]; ++k)
                    if (cell_nz(p, i, j, k)) {
                        int idx = (p_o1[p] + i) * 81 + (p_o2[p] + j) * 9 + (p_o3[p] + k);
                        packed[u * PACK_STRIDE + ci] = wgt * w3j[p * W3J_SZ + idx];
                        ++ci;
                    }
    }
}

// Block = 256 threads = 4 waves, 64 edges taken in CSR (node-sorted) order:
// e = bucket[b*64 + r]. Lanes then span ~5 distinct nodes -> x2s slice loads are
// L1-broadcast hits and stream sequentially across tiles. x1/out rows are scattered
// but each row = exactly 9 aligned 128B lines -> traffic stays compulsory.
// Four quarter-tiles (18.7 KB LDS -> 8 blocks/CU); in-place LDS morph x1 -> out;
// compile-time Wigner sparsity (83 FMA / 81 mul per chunk).
__global__ __launch_bounds__(256, 8) void contract_kernel(
    const float* __restrict__ x1, const int* __restrict__ idxs,
    float* __restrict__ ws, const int* __restrict__ dN,
    float* __restrict__ out, int E)
{
    __shared__ float tile[TILE * LSTR];   // 18,688 B
    __shared__ int lperm[TILE];
    const int tid = threadIdx.x;
    const long ebase = (long)blockIdx.x * TILE;
    const float* __restrict__ packed = ws;
    const float* __restrict__ x2s    = ws + PACK_TOTAL;
    const int N = dN[0];
    const int* __restrict__ bucket = (const int*)(x2s + (long)N * ROW) + 3 * N;

    if (tid < TILE) {
        long ee = ebase + tid;
        lperm[tid] = (ee < (long)E) ? bucket[ee] : -1;
    }
    __syncthreads();

    const int lane = tid & 63;
    const int wv   = __builtin_amdgcn_readfirstlane(tid >> 6);
    const int e    = lperm[lane];
    const bool vld = (e >= 0);
    const int n = idxs[vld ? e : 0];
    const float* __restrict__ r2 = x2s + (long)n * ROW;
    float* __restrict__ lrow = &tile[lane * LSTR];

    // prefetch chunk 0's x2 slice (u = wv): 2 dword-aligned vec4 + 1 scalar
    float x2c[BASE];
    {
        const float* s = r2 + wv * BASE;
        f4a4 a = *(const f4a4*)s;
        f4a4 b = *(const f4a4*)(s + 4);
        x2c[0]=a.x; x2c[1]=a.y; x2c[2]=a.z; x2c[3]=a.w;
        x2c[4]=b.x; x2c[5]=b.y; x2c[6]=b.z; x2c[7]=b.w;
        x2c[8]=s[8];
    }

    #pragma unroll 1
    for (int h = 0; h < 4; ++h) {
        // stage quarter-tile: rows via perm, 18 float4 per row, coalesced within row
        for (int q = tid; q < TILE * (QCOL / 4); q += 256) {
            int r = q / (QCOL / 4);
            int c = q - r * (QCOL / 4);
            int er = lperm[r];
            if (er >= 0) {
                float4 v = *(const float4*)(x1 + (long)er * ROW + h * QCOL + c * 4);
                float* d = &tile[r * LSTR + c * 4];
                d[0] = v.x; d[1] = v.y; d[2] = v.z; d[3] = v.w;
            }
        }
        __syncthreads();

        #pragma unroll 1
        for (int cc = 0; cc < 2; ++cc) {
            const int u = 8 * h + cc * 4 + wv;            // wave-uniform
            const float* __restrict__ wp = packed + u * PACK_STRIDE;

            float x2n[BASE];
            if (u + 4 < MULV) {
                const float* s = r2 + (u + 4) * BASE;
                f4a4 a = *(const f4a4*)s;
                f4a4 b = *(const f4a4*)(s + 4);
                x2n[0]=a.x; x2n[1]=a.y; x2n[2]=a.z; x2n[3]=a.w;
                x2n[4]=b.x; x2n[5]=b.y; x2n[6]=b.z; x2n[7]=b.w;
                x2n[8]=s[8];
            }

            const int lbase = (cc * 4 + wv) * BASE;       // offset within quarter row
            float x1v[BASE], acc[BASE];
            #pragma unroll
            for (int i = 0; i < BASE; ++i) {
                x1v[i] = lrow[lbase + i];                 // conflict-free b32
                acc[i] = 0.0f;
            }

            int ci = 0;
            #pragma unroll
            for (int p = 0; p < NPATH; ++p) {
                #pragma unroll
                for (int i = 0; i < p_d1[p]; ++i) {
                    #pragma unroll
                    for (int j = 0; j < p_d2[p]; ++j) {
                        if (pair_nz(p, i, j)) {
                            float xx = x1v[p_o1[p] + i] * x2c[p_o2[p] + j];
                            #pragma unroll
                            for (int k = 0; k < p_d3[p]; ++k) {
                                if (cell_nz(p, i, j, k)) {
                                    acc[p_o3[p] + k] = fmaf(wp[ci], xx, acc[p_o3[p] + k]);
                                    ++ci;
                                }
                            }
                        }
                    }
                }
            }
            #pragma unroll
            for (int k = 0; k < BASE; ++k)
                lrow[lbase + k] = acc[k];                 // in-place overwrite
            if (u + 4 < MULV) {
                #pragma unroll
                for (int i = 0; i < BASE; ++i) x2c[i] = x2n[i];
            }
        }
        __syncthreads();

        // write quarter-tile rows via perm: full lines written exactly once
        for (int q = tid; q < TILE * (QCOL / 4); q += 256) {
            int r = q / (QCOL / 4);
            int c = q - r * (QCOL / 4);
            int er = lperm[r];
            if (er >= 0) {
                const float* s = &tile[r * LSTR + c * 4];
                *(float4*)(out + (long)er * ROW + h * QCOL + c * 4) =
                    make_float4(s[0], s[1], s[2], s[3]);
            }
        }
        __syncthreads();
    }
}

extern "C" void kernel_launch(void* const* d_in, const int* in_sizes, int n_in,
                              void* d_out, int out_size, void* d_ws, size_t ws_size,
                              hipStream_t stream) {
    const float* x1      = (const float*)d_in[0];
    const float* x2      = (const float*)d_in[1];
    const int*   idxs    = (const int*)d_in[2];
    const float* weights = (const float*)d_in[3];
    const float* w3j     = (const float*)d_in[4];
    const int*   dN      = (const int*)d_in[5];
    float* out = (float*)d_out;
    float* ws  = (float*)d_ws;

    const int E = in_sizes[2];
    const int eb = (E + 255) / 256;

    // CSR build: count -> scan -> bucket fill
    zero_count_kernel<<<256, 256, 0, stream>>>(ws, dN);
    hist_kernel<<<eb, 256, 0, stream>>>(idxs, ws, dN, E);
    scan_kernel<<<1, 256, 0, stream>>>(ws, dN);
    fill_kernel<<<eb, 256, 0, stream>>>(idxs, ws, dN, E);

    // per-node gather-sum
    gather_sum_kernel<<<2048, 256, 0, stream>>>(x2, ws, dN);

    // packed per-u nonzero coefficients (83/u)
    ww_build_kernel<<<1, 64, 0, stream>>>(weights, w3j, ws);

    // contraction: CSR-ordered edges, quarter-tiles, in-place LDS morph
    contract_kernel<<<(E + TILE - 1) / TILE, 256, 0, stream>>>(x1, idxs, ws, dN, out, E);
}

// Round 10
// 179.878 us; speedup vs baseline: 2.5286x; 1.0905x over previous
//
#include <hip/hip_runtime.h>

#define MULV 32
#define BASE 9
#define ROW 288          // MULV*BASE
#define NPATH 11
#define W3J_SZ 729       // 9*9*9
#define PACK_STRIDE 96   // 83 nonzero packed coeffs per u, padded
#define PACK_TOTAL (MULV * PACK_STRIDE)
#define TILE 64          // edges per block (lane <-> edge)
#define QCOL 72          // columns per quarter-tile (8 u's x 9)
#define LSTR 73          // LDS row stride: bank stride 9 (coprime 32) -> conflict-free b32
#define NQ4 18           // float4s per row per quarter (QCOL/4)
#define QTOT (TILE * NQ4)  // 1152 float4s per quarter

typedef float f4a4 __attribute__((ext_vector_type(4), aligned(4)));  // dword-aligned vec4 load

// Path table: (i1,i2,io) blocks for IRREPS [(0,e),(1,o),(2,e)], dims {1,3,5}, offs {0,1,4}
__device__ constexpr int p_o1[NPATH] = {0,1,4, 0,1,1,4, 0,1,4,4};
__device__ constexpr int p_d1[NPATH] = {1,3,5, 1,3,3,5, 1,3,5,5};
__device__ constexpr int p_o2[NPATH] = {0,1,4, 1,0,4,1, 4,1,0,4};
__device__ constexpr int p_d2[NPATH] = {1,3,5, 3,1,5,3, 5,3,1,5};
__device__ constexpr int p_o3[NPATH] = {0,0,0, 1,1,1,1, 4,4,4,4};
__device__ constexpr int p_d3[NPATH] = {1,1,1, 3,3,3,3, 5,5,5,5};
__device__ constexpr int p_l1[NPATH] = {0,1,2, 0,1,1,2, 0,1,2,2};
__device__ constexpr int p_l2[NPATH] = {0,1,2, 1,0,2,1, 2,1,0,2};
__device__ constexpr int p_l3[NPATH] = {0,0,0, 1,1,1,1, 2,2,2,2};

// Wigner real-basis selection rules (all paths have even l1+l2+l3):
// nonzero only if #{m<0} even AND |m3| in {|m1|+|m2|, ||m1|-|m2||}.
// Necessary conditions only: a false-positive cell merely wastes an FMA on 0.0.
__device__ __host__ constexpr bool cell_nz(int p, int i, int j, int k) {
    int m1 = i - p_l1[p], m2 = j - p_l2[p], m3 = k - p_l3[p];
    if ((((m1 < 0) + (m2 < 0) + (m3 < 0)) & 1) != 0) return false;
    int a1 = m1 < 0 ? -m1 : m1, a2 = m2 < 0 ? -m2 : m2, a3 = m3 < 0 ? -m3 : m3;
    int d = a1 - a2; if (d < 0) d = -d;
    return (a3 == a1 + a2) || (a3 == d);
}
__device__ __host__ constexpr bool pair_nz(int p, int i, int j) {
    for (int k = 0; k < p_d3[p]; ++k) if (cell_nz(p, i, j, k)) return true;
    return false;
}

// ---- ws layout ----
// packed : ws[0 .. PACK_TOTAL)
// x2s    : ws + PACK_TOTAL, N*ROW floats
// count  : (int*) after x2s, N ints
// offset : count + N ; cursor : count + 2N ; bucket : count + 3N (E ints)

__global__ void zero_count_kernel(float* __restrict__ ws, const int* __restrict__ dN) {
    int N = dN[0];
    int* count = (int*)(ws + PACK_TOTAL + (long)N * ROW);
    for (int i = blockIdx.x * blockDim.x + threadIdx.x; i < N; i += gridDim.x * blockDim.x)
        count[i] = 0;
}

__global__ void hist_kernel(const int* __restrict__ idxs, float* __restrict__ ws,
                            const int* __restrict__ dN, int E) {
    int N = dN[0];
    int* count = (int*)(ws + PACK_TOTAL + (long)N * ROW);
    int t = blockIdx.x * blockDim.x + threadIdx.x;
    if (t < E) atomicAdd(&count[idxs[t]], 1);
}

// single block, 1024 threads: per-thread serial prefix (~N/1024) + one 1024-wide scan
__global__ void scan_kernel(float* __restrict__ ws, const int* __restrict__ dN) {
    int N = dN[0];
    int* count  = (int*)(ws + PACK_TOTAL + (long)N * ROW);
    int* offset = count + N;
    int* cursor = count + 2 * N;
    __shared__ int tsum[1024];
    const int tid = threadIdx.x;
    int cpt = (N + 1023) / 1024;
    int lo = tid * cpt;
    int hi = lo + cpt; if (hi > N) hi = N;
    int s = 0;
    for (int i = lo; i < hi; ++i) s += count[i];
    int v = s;
    tsum[tid] = v;
    __syncthreads();
    #pragma unroll
    for (int off = 1; off < 1024; off <<= 1) {
        int t = (tid >= off) ? tsum[tid - off] : 0;
        __syncthreads();
        v += t;
        tsum[tid] = v;
        __syncthreads();
    }
    int run = v - s;
    for (int i = lo; i < hi; ++i) {
        int c = count[i];
        offset[i] = run; cursor[i] = run;
        run += c;
    }
}

__global__ void fill_kernel(const int* __restrict__ idxs, float* __restrict__ ws,
                            const int* __restrict__ dN, int E) {
    int N = dN[0];
    int* count  = (int*)(ws + PACK_TOTAL + (long)N * ROW);
    int* cursor = count + 2 * N;
    int* bucket = count + 3 * N;
    int t = blockIdx.x * blockDim.x + threadIdx.x;
    if (t < E) {
        int n = idxs[t];
        int pos = atomicAdd(&cursor[n], 1);
        bucket[pos] = t;
    }
}

// one wave per node: x2s[n,:] = sum over edges in bucket of x2[e,:]
__global__ __launch_bounds__(256) void gather_sum_kernel(const float* __restrict__ x2,
                                                         float* __restrict__ ws,
                                                         const int* __restrict__ dN) {
    int N = dN[0];
    float* x2s  = ws + PACK_TOTAL;
    int* count  = (int*)(x2s + (long)N * ROW);
    int* offset = count + N;
    int* bucket = count + 3 * N;
    const int lane = threadIdx.x & 63;
    const int wv   = threadIdx.x >> 6;
    for (int n0 = blockIdx.x * 4 + wv; n0 < N; n0 += gridDim.x * 4) {
        int n   = __builtin_amdgcn_readfirstlane(n0);
        int off = offset[n];
        int deg = count[n];
        float4 a0 = make_float4(0.f, 0.f, 0.f, 0.f);
        float4 a1 = make_float4(0.f, 0.f, 0.f, 0.f);
        for (int d = 0; d < deg; ++d) {
            int e = bucket[off + d];
            const float4* row = (const float4*)(x2 + (long)e * ROW);
            float4 v = row[lane];
            a0.x += v.x; a0.y += v.y; a0.z += v.z; a0.w += v.w;
            if (lane < 8) {
                float4 w = row[64 + lane];
                a1.x += w.x; a1.y += w.y; a1.z += w.z; a1.w += w.w;
            }
        }
        float4* orow = (float4*)(x2s + (long)n * ROW);
        orow[lane] = a0;
        if (lane < 8) orow[64 + lane] = a1;
    }
}

// packed[u][ci] = weights[u,p] * w3j[p, cell] over nonzero cells in fixed loop order
__global__ void ww_build_kernel(const float* __restrict__ weights,
                                const float* __restrict__ w3j,
                                float* __restrict__ packed) {
    int u = threadIdx.x;
    if (u >= MULV) return;
    int ci = 0;
    #pragma unroll
    for (int p = 0; p < NPATH; ++p) {
        float wgt = weights[u * NPATH + p];
        #pragma unroll
        for (int i = 0; i < p_d1[p]; ++i)
            #pragma unroll
            for (int j = 0; j < p_d2[p]; ++j)
                #pragma unroll
                for (int k = 0; k < p_d3[p]; ++k)
                    if (cell_nz(p, i, j, k)) {
                        int idx = (p_o1[p] + i) * 81 + (p_o2[p] + j) * 9 + (p_o3[p] + k);
                        packed[u * PACK_STRIDE + ci] = wgt * w3j[p * W3J_SZ + idx];
                        ++ci;
                    }
    }
}

// Block = 256 threads = 4 waves, 64 CSR-ordered edges (e = bucket[b*64+r]).
// Quarter-tiles staged via REGISTERS (T14 async split): quarter h+1's global loads
// are issued before compute(h) and consumed (ds_write) at the top of h+1 ->
// HBM latency hides under compute+writeout. Write-out(h) and stage(h+1) touch the
// same tile address from the SAME thread -> no barrier between them: 2 barriers per
// quarter, none of which waits on global loads. In-place LDS morph x1 -> out;
// compile-time Wigner sparsity (83 FMA / 81 mul per chunk).
__global__ __launch_bounds__(256, 4) void contract_kernel(
    const float* __restrict__ x1, const int* __restrict__ idxs,
    float* __restrict__ ws, const int* __restrict__ dN,
    float* __restrict__ out, int E)
{
    __shared__ float tile[TILE * LSTR];   // 18,688 B
    __shared__ int lperm[TILE];
    const int tid = threadIdx.x;
    const long ebase = (long)blockIdx.x * TILE;
    const float* __restrict__ packed = ws;
    const float* __restrict__ x2s    = ws + PACK_TOTAL;
    const int N = dN[0];
    const int* __restrict__ bucket = (const int*)(x2s + (long)N * ROW) + 3 * N;

    if (tid < TILE) {
        long ee = ebase + tid;
        lperm[tid] = (ee < (long)E) ? bucket[ee] : -1;
    }
    __syncthreads();

    const int lane = tid & 63;
    const int wv   = __builtin_amdgcn_readfirstlane(tid >> 6);
    const int e    = lperm[lane];
    const int n    = idxs[e >= 0 ? e : 0];
    const float* __restrict__ r2 = x2s + (long)n * ROW;
    float* __restrict__ lrow = &tile[lane * LSTR];

    // prologue: issue quarter 0's stage loads into registers
    float4 buf[5];
    #pragma unroll
    for (int t = 0; t < 5; ++t) {
        int q = tid + t * 256;
        if (q < QTOT) {
            int r = q / NQ4, c = q - r * NQ4;
            int er = lperm[r];
            if (er >= 0)
                buf[t] = *(const float4*)(x1 + (long)er * ROW + c * 4);
        }
    }

    #pragma unroll 1
    for (int h = 0; h < 4; ++h) {
        // stage: ds_write regs -> tile (compiler inserts the vmcnt wait here)
        #pragma unroll
        for (int t = 0; t < 5; ++t) {
            int q = tid + t * 256;
            if (q < QTOT) {
                int r = q / NQ4, c = q - r * NQ4;
                float* d = &tile[r * LSTR + c * 4];
                d[0] = buf[t].x; d[1] = buf[t].y; d[2] = buf[t].z; d[3] = buf[t].w;
            }
        }
        __syncthreads();

        // issue quarter h+1's loads now; they complete under compute + writeout
        if (h < 3) {
            #pragma unroll
            for (int t = 0; t < 5; ++t) {
                int q = tid + t * 256;
                if (q < QTOT) {
                    int r = q / NQ4, c = q - r * NQ4;
                    int er = lperm[r];
                    if (er >= 0)
                        buf[t] = *(const float4*)(x1 + (long)er * ROW + (h + 1) * QCOL + c * 4);
                }
            }
        }

        // compute 2 chunks in place (u = 8h + cc*4 + wv, wave-uniform)
        #pragma unroll 1
        for (int cc = 0; cc < 2; ++cc) {
            const int u = 8 * h + cc * 4 + wv;
            const float* __restrict__ wp = packed + u * PACK_STRIDE;

            float x2c[BASE];
            {
                const float* s = r2 + u * BASE;   // L1-broadcast hit (CSR ordering)
                f4a4 a = *(const f4a4*)s;
                f4a4 b = *(const f4a4*)(s + 4);
                x2c[0]=a.x; x2c[1]=a.y; x2c[2]=a.z; x2c[3]=a.w;
                x2c[4]=b.x; x2c[5]=b.y; x2c[6]=b.z; x2c[7]=b.w;
                x2c[8]=s[8];
            }

            const int lbase = (cc * 4 + wv) * BASE;
            float x1v[BASE], acc[BASE];
            #pragma unroll
            for (int i = 0; i < BASE; ++i) {
                x1v[i] = lrow[lbase + i];                 // conflict-free b32
                acc[i] = 0.0f;
            }

            int ci = 0;
            #pragma unroll
            for (int p = 0; p < NPATH; ++p) {
                #pragma unroll
                for (int i = 0; i < p_d1[p]; ++i) {
                    #pragma unroll
                    for (int j = 0; j < p_d2[p]; ++j) {
                        if (pair_nz(p, i, j)) {
                            float xx = x1v[p_o1[p] + i] * x2c[p_o2[p] + j];
                            #pragma unroll
                            for (int k = 0; k < p_d3[p]; ++k) {
                                if (cell_nz(p, i, j, k)) {
                                    acc[p_o3[p] + k] = fmaf(wp[ci], xx, acc[p_o3[p] + k]);
                                    ++ci;
                                }
                            }
                        }
                    }
                }
            }
            #pragma unroll
            for (int k = 0; k < BASE; ++k)
                lrow[lbase + k] = acc[k];                 // in-place overwrite
        }
        __syncthreads();

        // write-out: same thread touches the same tile (r,c) it will stage next ->
        // no barrier needed before the next iteration's ds_write
        #pragma unroll
        for (int t = 0; t < 5; ++t) {
            int q = tid + t * 256;
            if (q < QTOT) {
                int r = q / NQ4, c = q - r * NQ4;
                int er = lperm[r];
                if (er >= 0) {
                    const float* s = &tile[r * LSTR + c * 4];
                    *(float4*)(out + (long)er * ROW + h * QCOL + c * 4) =
                        make_float4(s[0], s[1], s[2], s[3]);
                }
            }
        }
    }
}

extern "C" void kernel_launch(void* const* d_in, const int* in_sizes, int n_in,
                              void* d_out, int out_size, void* d_ws, size_t ws_size,
                              hipStream_t stream) {
    const float* x1      = (const float*)d_in[0];
    const float* x2      = (const float*)d_in[1];
    const int*   idxs    = (const int*)d_in[2];
    const float* weights = (const float*)d_in[3];
    const float* w3j     = (const float*)d_in[4];
    const int*   dN      = (const int*)d_in[5];
    float* out = (float*)d_out;
    float* ws  = (float*)d_ws;

    const int E = in_sizes[2];
    const int eb = (E + 255) / 256;

    // CSR build: count -> scan -> bucket fill
    zero_count_kernel<<<256, 256, 0, stream>>>(ws, dN);
    hist_kernel<<<eb, 256, 0, stream>>>(idxs, ws, dN, E);
    scan_kernel<<<1, 1024, 0, stream>>>(ws, dN);
    fill_kernel<<<eb, 256, 0, stream>>>(idxs, ws, dN, E);

    // per-node gather-sum
    gather_sum_kernel<<<2500, 256, 0, stream>>>(x2, ws, dN);

    // packed per-u nonzero coefficients (83/u)
    ww_build_kernel<<<1, 64, 0, stream>>>(weights, w3j, ws);

    // contraction: CSR-ordered edges, register-staged quarter-tiles (T14), in-place morph
    contract_kernel<<<(E + TILE - 1) / TILE, 256, 0, stream>>>(x1, idxs, ws, dN, out, E);
}